// Round 1
// baseline (2179.598 us; speedup 1.0000x reference)
//
#include <hip/hip_runtime.h>

typedef unsigned long long u64;
typedef unsigned int u32;

#define NB 4
#define NP 4096
#define MP 2048
#define KN 32
#define FD 64
#define CAP 512

// Exact (non-contracted) squared distance, matching numpy's f32 evaluation
// order: ((dx*dx + dy*dy) + dz*dz), each op individually rounded.
__device__ __forceinline__ float dist2(float ax, float ay, float az,
                                       float bx, float by, float bz) {
  float dx = ax - bx, dy = ay - by, dz = az - bz;
  return __fadd_rn(__fadd_rn(__fmul_rn(dx, dx), __fmul_rn(dy, dy)),
                   __fmul_rn(dz, dz));
}

__device__ __forceinline__ void fma16(float* acc, float a, const float4* wp) {
#pragma unroll
  for (int u = 0; u < 4; ++u) {
    float4 wv = wp[u];
    acc[u * 4 + 0] = fmaf(a, wv.x, acc[u * 4 + 0]);
    acc[u * 4 + 1] = fmaf(a, wv.y, acc[u * 4 + 1]);
    acc[u * 4 + 2] = fmaf(a, wv.z, acc[u * 4 + 2]);
    acc[u * 4 + 3] = fmaf(a, wv.w, acc[u * 4 + 3]);
  }
}

// ---------------------------------------------------------------------------
// Kernel 1: farthest point sampling. One block per cloud, 1024 threads,
// 4 points/thread held in registers. Sequential over 2047 selections.
// Argmax tie-break = lowest index (key packs 4095-idx in low bits, max-reduce).
// ---------------------------------------------------------------------------
__global__ __launch_bounds__(1024) void fps_kernel(const float* __restrict__ pos,
                                                   int* __restrict__ fps_idx) {
  const int b = blockIdx.x;
  const float* p = pos + (size_t)b * NP * 3;
  __shared__ float px[NP], py[NP], pz[NP];
  __shared__ u64 red[2];
  const int t = threadIdx.x;
  for (int i = t; i < NP; i += 1024) {
    px[i] = p[3 * i + 0];
    py[i] = p[3 * i + 1];
    pz[i] = p[3 * i + 2];
  }
  if (t < 2) red[t] = 0ull;
  __syncthreads();

  const float q0x = px[0], q0y = py[0], q0z = pz[0];
  float cx[4], cy[4], cz[4], mind[4];
  float maxv = -1.0f;
  int maxi = 0;
#pragma unroll
  for (int j = 0; j < 4; ++j) {
    const int i = t + j * 1024;
    cx[j] = px[i]; cy[j] = py[i]; cz[j] = pz[i];
    mind[j] = dist2(cx[j], cy[j], cz[j], q0x, q0y, q0z);
    if (mind[j] > maxv) { maxv = mind[j]; maxi = i; }
  }
  if (t == 0) fps_idx[b * MP] = 0;
  const int lane = t & 63;

  for (int it = 1; it < MP; ++it) {
    u64 key = ((u64)__float_as_uint(maxv) << 32) | (u32)(NP - 1 - maxi);
#pragma unroll
    for (int off = 32; off >= 1; off >>= 1) {
      u64 ok = __shfl_xor(key, off, 64);
      key = (ok > key) ? ok : key;
    }
    if (lane == 0) atomicMax(&red[it & 1], key);
    __syncthreads();
    const u64 wkey = red[it & 1];
    if (t == 0) {
      red[(it + 1) & 1] = 0ull;  // reset other slot for next iteration
      fps_idx[b * MP + it] = NP - 1 - (int)(wkey & 0xFFFFFFFFu);
    }
    __syncthreads();
    const int widx = NP - 1 - (int)(wkey & 0xFFFFFFFFu);
    const float wx = px[widx], wy = py[widx], wz = pz[widx];
    maxv = -1.0f; maxi = 0;
#pragma unroll
    for (int j = 0; j < 4; ++j) {
      const float d = dist2(cx[j], cy[j], cz[j], wx, wy, wz);
      mind[j] = fminf(mind[j], d);
      if (mind[j] > maxv) { maxv = mind[j]; maxi = t + j * 1024; }
    }
  }
}

// ---------------------------------------------------------------------------
// Kernel 2: radius-kNN. One wave per query (4 waves/block). Compacts all
// within-radius candidates into LDS (ballot compaction), then extracts the
// 32 smallest (d2,idx) keys via wave-wide u64 min-reduction.
// Also writes pos_out and batch_out (exact gathers).
// ---------------------------------------------------------------------------
__global__ __launch_bounds__(256) void knn_kernel(const float* __restrict__ pos,
                                                  const int* __restrict__ fps_idx,
                                                  int* __restrict__ nbr,
                                                  float* __restrict__ pos_out,
                                                  float* __restrict__ batch_out) {
  __shared__ u64 list[4][CAP];
  const int t = threadIdx.x;
  const int w = t >> 6;
  const int lane = t & 63;
  const int qg = blockIdx.x * 4 + w;  // 0..8191
  const int b = qg >> 11;
  const float* p = pos + (size_t)b * NP * 3;
  const int pidx = fps_idx[qg];
  const float qx = p[3 * pidx], qy = p[3 * pidx + 1], qz = p[3 * pidx + 2];

  int base = 0;
  for (int rnd = 0; rnd < NP / 64; ++rnd) {
    const int j = rnd * 64 + lane;
    const float d2 = dist2(p[3 * j], p[3 * j + 1], p[3 * j + 2], qx, qy, qz);
    const bool pred = (d2 <= 0.04f);  // 0.04f == f32(R*R) boundary, exact
    const u64 bal = __ballot(pred);
    if (pred) {
      const int slot = base + (int)__popcll(bal & ((1ull << lane) - 1ull));
      if (slot < CAP) list[w][slot] = ((u64)__float_as_uint(d2) << 32) | (u32)j;
    }
    base += (int)__popcll(bal);
  }
  const int L = base < CAP ? base : CAP;
  __syncthreads();

  u64 mk[8];
#pragma unroll
  for (int s = 0; s < 8; ++s) {
    const int sl = lane + s * 64;
    mk[s] = (sl < L) ? list[w][sl] : ~0ull;
  }
  u64 lmin = mk[0];
#pragma unroll
  for (int s = 1; s < 8; ++s) lmin = (mk[s] < lmin) ? mk[s] : lmin;

  int myNbr = -1;
  for (int r = 0; r < KN; ++r) {
    u64 m = lmin;
#pragma unroll
    for (int off = 32; off >= 1; off >>= 1) {
      u64 om = __shfl_xor(m, off, 64);
      m = (om < m) ? om : m;
    }
    if (m == ~0ull) break;  // wave-uniform: fewer than 32 in-radius
    if (lane == r) myNbr = (int)(m & 0xFFFFFFFFu);
    if (lmin == m) {  // exactly one lane (keys unique)
#pragma unroll
      for (int s = 0; s < 8; ++s) if (mk[s] == m) mk[s] = ~0ull;
      lmin = mk[0];
#pragma unroll
      for (int s = 1; s < 8; ++s) lmin = (mk[s] < lmin) ? mk[s] : lmin;
    }
  }
  if (lane < KN) nbr[(size_t)qg * KN + lane] = myNbr;
  if (lane == 0) {
    pos_out[qg * 3 + 0] = qx;
    pos_out[qg * 3 + 1] = qy;
    pos_out[qg * 3 + 2] = qz;
    batch_out[qg] = (float)b;
  }
}

// ---------------------------------------------------------------------------
// Kernel 3: gather + 3-layer MLP + masked max aggregation.
// Block = 256 threads handles 2 queries (64 neighbor rows). Weights staged
// per-layer into a shared 17KB buffer (W3 streamed in two k-halves).
// Aggregation: relu outputs >= 0 and self-neighbor always valid, so
// 0-initialized atomicMax on float bits is exact.
// ---------------------------------------------------------------------------
__global__ __launch_bounds__(256) void mlp_kernel(
    const float* __restrict__ x, const float* __restrict__ pos,
    const int* __restrict__ fps_idx, const int* __restrict__ nbr,
    const float* __restrict__ W1, const float* __restrict__ b1,
    const float* __restrict__ W2, const float* __restrict__ b2,
    const float* __restrict__ W3, const float* __restrict__ b3,
    float* __restrict__ aggG) {
  __shared__ __align__(16) float inB[64][68];  // 67 cols used (x .. rel)
  __shared__ __align__(16) float hB[64][68];
  __shared__ __align__(16) float wB[4352];     // W1(4288) / W2(4096) / W3-half(4096)
  __shared__ u32 agg[2][128];
  __shared__ int vrow[64];
  const int t = threadIdx.x;
  const int q0 = blockIdx.x * 2;

  ((u32*)agg)[t] = 0u;  // 256 entries exactly
  for (int i = t; i < 1072; i += 256) ((float4*)wB)[i] = ((const float4*)W1)[i];
  {
    const int r = t >> 2, qu = t & 3;
    const int qg = q0 + (r >> 5);
    const int nid = nbr[(size_t)qg * KN + (r & 31)];
    const int gid = (nid < 0) ? 0 : nid;
    const int bb = qg >> 11;
    const float4* xr =
        (const float4*)(x + ((size_t)bb * NP + gid) * FD + qu * 16);
#pragma unroll
    for (int u = 0; u < 4; ++u) {
      float4 v = xr[u];
      inB[r][qu * 16 + u * 4 + 0] = v.x;
      inB[r][qu * 16 + u * 4 + 1] = v.y;
      inB[r][qu * 16 + u * 4 + 2] = v.z;
      inB[r][qu * 16 + u * 4 + 3] = v.w;
    }
    if (qu == 0) {
      vrow[r] = nid;
      const float* p = pos + (size_t)bb * NP * 3;
      const int pidx = fps_idx[qg];
      inB[r][64] = p[3 * gid + 0] - p[3 * pidx + 0];
      inB[r][65] = p[3 * gid + 1] - p[3 * pidx + 1];
      inB[r][66] = p[3 * gid + 2] - p[3 * pidx + 2];
    }
  }
  __syncthreads();

  const int c0a = (t & 3) * 16;  // layers 1-2: 64 channels
  const int ra = t >> 2;         // row 0..63
  {  // ---- layer 1: 67 -> 64, relu ----
    float acc[16];
#pragma unroll
    for (int c = 0; c < 16; ++c) acc[c] = b1[c0a + c];
    for (int k = 0; k < 67; ++k)
      fma16(acc, inB[ra][k], (const float4*)&wB[k * 64 + c0a]);
#pragma unroll
    for (int c = 0; c < 16; ++c) hB[ra][c0a + c] = fmaxf(acc[c], 0.0f);
  }
  __syncthreads();
  for (int i = t; i < 1024; i += 256) ((float4*)wB)[i] = ((const float4*)W2)[i];
  __syncthreads();
  {  // ---- layer 2: 64 -> 64, relu (writes back into inB) ----
    float acc[16];
#pragma unroll
    for (int c = 0; c < 16; ++c) acc[c] = b2[c0a + c];
    for (int k = 0; k < 64; ++k)
      fma16(acc, hB[ra][k], (const float4*)&wB[k * 64 + c0a]);
#pragma unroll
    for (int c = 0; c < 16; ++c) inB[ra][c0a + c] = fmaxf(acc[c], 0.0f);
  }
  __syncthreads();

  // ---- layer 3: 64 -> 128 in two k-halves, then masked max aggregation ----
  const int c0b = (t & 7) * 16;
  const int r0 = (t >> 3) * 2;  // even row pair, never straddles a query
  float acc0[16], acc1[16];
#pragma unroll
  for (int c = 0; c < 16; ++c) { acc0[c] = b3[c0b + c]; acc1[c] = b3[c0b + c]; }
  for (int half = 0; half < 2; ++half) {
    for (int i = t; i < 1024; i += 256)
      ((float4*)wB)[i] = ((const float4*)(W3 + half * 32 * 128))[i];
    __syncthreads();
    for (int k = 0; k < 32; ++k) {
      const float a0 = inB[r0][half * 32 + k];
      const float a1 = inB[r0 + 1][half * 32 + k];
      const float4* wp = (const float4*)&wB[k * 128 + c0b];
      fma16(acc0, a0, wp);
      fma16(acc1, a1, wp);
    }
    __syncthreads();
  }
  {
    const int qq = r0 >> 5;
    const int v0 = vrow[r0], v1 = vrow[r0 + 1];
#pragma unroll
    for (int c = 0; c < 16; ++c) {
      float m = 0.0f;  // == max(0, .) folds the relu; exact (>=1 valid row/query)
      if (v0 >= 0) m = fmaxf(m, acc0[c]);
      if (v1 >= 0) m = fmaxf(m, acc1[c]);
      atomicMax(&agg[qq][c0b + c], __float_as_uint(m));
    }
  }
  __syncthreads();
  aggG[(size_t)(q0 + (t >> 7)) * 128 + (t & 127)] =
      __uint_as_float(agg[t >> 7][t & 127]);
}

// ---------------------------------------------------------------------------
// Kernel 4: out = agg @ Wg + bg. 32 rows/block; Wg staged in two k-halves.
// ---------------------------------------------------------------------------
__global__ __launch_bounds__(256) void wg_kernel(const float* __restrict__ aggG,
                                                 const float* __restrict__ Wg,
                                                 const float* __restrict__ bg,
                                                 float* __restrict__ xout) {
  __shared__ __align__(16) float wL[64 * 128];
  __shared__ __align__(16) float aL[32][132];
  const int t = threadIdx.x;
  const size_t row0 = (size_t)blockIdx.x * 32;
  for (int i = t; i < 1024; i += 256) {
    const int r = i >> 5, qd = i & 31;
    float4 v = ((const float4*)(aggG + (row0 + r) * 128))[qd];
    *((float4*)&aL[r][qd * 4]) = v;
  }
  const int r = t >> 3;
  const int c0 = (t & 7) * 16;
  float acc[16];
#pragma unroll
  for (int c = 0; c < 16; ++c) acc[c] = bg[c0 + c];
  for (int half = 0; half < 2; ++half) {
    __syncthreads();  // protects wL overwrite; also orders aL staging (half 0)
    for (int i = t; i < 2048; i += 256)
      ((float4*)wL)[i] = ((const float4*)(Wg + half * 64 * 128))[i];
    __syncthreads();
    for (int k = 0; k < 64; ++k)
      fma16(acc, aL[r][half * 64 + k], (const float4*)&wL[k * 128 + c0]);
  }
#pragma unroll
  for (int u = 0; u < 4; ++u) {
    float4 v = make_float4(acc[u * 4 + 0], acc[u * 4 + 1], acc[u * 4 + 2],
                           acc[u * 4 + 3]);
    ((float4*)(xout + (row0 + r) * 128 + c0))[u] = v;
  }
}

// ---------------------------------------------------------------------------

extern "C" void kernel_launch(void* const* d_in, const int* in_sizes, int n_in,
                              void* d_out, int out_size, void* d_ws,
                              size_t ws_size, hipStream_t stream) {
  const float* x   = (const float*)d_in[0];
  const float* pos = (const float*)d_in[1];
  // d_in[2] = batch (implied by layout, unused)
  const float* W1 = (const float*)d_in[3];
  const float* b1 = (const float*)d_in[4];
  const float* W2 = (const float*)d_in[5];
  const float* b2 = (const float*)d_in[6];
  const float* W3 = (const float*)d_in[7];
  const float* b3 = (const float*)d_in[8];
  const float* Wg = (const float*)d_in[9];
  const float* bg = (const float*)d_in[10];

  float* out = (float*)d_out;
  float* x_out = out;                                  // 8192*128
  float* pos_out = out + (size_t)NB * MP * 128;        // 8192*3
  float* batch_out = pos_out + (size_t)NB * MP * 3;    // 8192 (as float)

  char* ws = (char*)d_ws;
  int* fps_idx = (int*)ws;                             // 8192 ints
  int* nbr = (int*)(ws + 32768);                       // 8192*32 ints = 1 MB
  float* aggG = (float*)(ws + 32768 + (size_t)NB * MP * KN * 4);  // 4 MB

  hipLaunchKernelGGL(fps_kernel, dim3(NB), dim3(1024), 0, stream, pos, fps_idx);
  hipLaunchKernelGGL(knn_kernel, dim3(NB * MP / 4), dim3(256), 0, stream, pos,
                     fps_idx, nbr, pos_out, batch_out);
  hipLaunchKernelGGL(mlp_kernel, dim3(NB * MP / 2), dim3(256), 0, stream, x,
                     pos, fps_idx, nbr, W1, b1, W2, b2, W3, b3, aggG);
  hipLaunchKernelGGL(wg_kernel, dim3(NB * MP / 32), dim3(256), 0, stream, aggG,
                     Wg, bg, x_out);
}

// Round 2
// 1384.423 us; speedup vs baseline: 1.5744x; 1.5744x over previous
//
#include <hip/hip_runtime.h>

typedef unsigned long long u64;
typedef unsigned int u32;

#define NB 4
#define NP 4096
#define MP 2048
#define KN 32
#define FD 64
#define CAP 512
#define PPT 16  // points per thread in fps (256 threads * 16 = 4096)

// Exact (non-contracted) squared distance, matching numpy's f32 evaluation
// order: ((dx*dx + dy*dy) + dz*dz), each op individually rounded.
__device__ __forceinline__ float dist2(float ax, float ay, float az,
                                       float bx, float by, float bz) {
  float dx = ax - bx, dy = ay - by, dz = az - bz;
  return __fadd_rn(__fadd_rn(__fmul_rn(dx, dx), __fmul_rn(dy, dy)),
                   __fmul_rn(dz, dz));
}

__device__ __forceinline__ void fma16(float* acc, float a, const float4* wp) {
#pragma unroll
  for (int u = 0; u < 4; ++u) {
    float4 wv = wp[u];
    acc[u * 4 + 0] = fmaf(a, wv.x, acc[u * 4 + 0]);
    acc[u * 4 + 1] = fmaf(a, wv.y, acc[u * 4 + 1]);
    acc[u * 4 + 2] = fmaf(a, wv.z, acc[u * 4 + 2]);
    acc[u * 4 + 3] = fmaf(a, wv.w, acc[u * 4 + 3]);
  }
}

// Wave64 max-reduce of a nonnegative f32 via DPP (identity 0 from bound_ctrl),
// result broadcast to all lanes through readlane(63). ~6 dependent VALU ops
// instead of 6 dependent LDS-crossbar swizzles.
__device__ __forceinline__ float wave_max_bcast(float x) {
  int v = __float_as_int(x);
#define DPP_STEP(ctrl)                                                     \
  {                                                                        \
    int o = __builtin_amdgcn_update_dpp(0, v, ctrl, 0xF, 0xF, true);       \
    v = __float_as_int(fmaxf(__int_as_float(v), __int_as_float(o)));       \
  }
  DPP_STEP(0x111)  // row_shr:1
  DPP_STEP(0x112)  // row_shr:2
  DPP_STEP(0x114)  // row_shr:4
  DPP_STEP(0x118)  // row_shr:8  -> lane 15/31/47/63 hold row maxes
  DPP_STEP(0x142)  // row_bcast15 -> lane31 = max(0..31), lane63 = max(32..63)
  DPP_STEP(0x143)  // row_bcast31 -> lane63 = max(0..63)
#undef DPP_STEP
  return __int_as_float(__builtin_amdgcn_readlane(v, 63));
}

// ---------------------------------------------------------------------------
// Kernel 1: farthest point sampling. One block per cloud, 256 threads,
// 16 points/thread in registers. Per iteration: DPP wave-argmax (+ballot for
// first-index tie-break), winner lane writes a u64 key to a ping-pong LDS
// slot, ONE barrier, all threads merge 4 keys and read the winning center
// from an LDS coord copy. No atomics, no u64 shuffles, one barrier/iter.
// ---------------------------------------------------------------------------
__global__ __launch_bounds__(256) void fps_kernel(const float* __restrict__ pos,
                                                  int* __restrict__ fps_idx) {
  const int b = blockIdx.x;
  const float* p = pos + (size_t)b * NP * 3;
  __shared__ __align__(16) float2 sxy[NP];  // 32 KB
  __shared__ float sz[NP];                  // 16 KB
  __shared__ u64 keys[2][4];
  const int t = threadIdx.x;
  const int w = t >> 6;
  const int lane = t & 63;

  for (int i = t; i < NP; i += 256) {
    sxy[i] = make_float2(p[3 * i + 0], p[3 * i + 1]);
    sz[i] = p[3 * i + 2];
  }
  __syncthreads();

  // thread t owns global points [t*16, t*16+16) -> lane order == index order
  const int base = t * PPT;
  float cx[PPT], cy[PPT], cz[PPT], mind[PPT];
  const float2 q0 = sxy[0];
  const float q0z = sz[0];
  float maxv = -1.0f;
  int maxi = base;
#pragma unroll
  for (int j = 0; j < PPT; ++j) {
    float2 xy = sxy[base + j];
    cx[j] = xy.x; cy[j] = xy.y; cz[j] = sz[base + j];
    mind[j] = dist2(cx[j], cy[j], cz[j], q0.x, q0.y, q0z);
    if (mind[j] > maxv) { maxv = mind[j]; maxi = base + j; }  // strict >: first max
  }
  if (t == 0) fps_idx[b * MP] = 0;

  for (int it = 1; it < MP; ++it) {
    const float wmax = wave_max_bcast(maxv);
    const u64 bal = __ballot(maxv == wmax);
    const int winner = (int)__ffsll(bal) - 1;  // lowest lane = lowest index
    if (lane == winner)
      keys[it & 1][w] =
          ((u64)__float_as_uint(wmax) << 32) | (u32)(NP - 1 - maxi);
    __syncthreads();
    const u64 k0 = keys[it & 1][0], k1 = keys[it & 1][1];
    const u64 k2 = keys[it & 1][2], k3 = keys[it & 1][3];
    const u64 ka = (k1 > k0) ? k1 : k0;
    const u64 kb = (k3 > k2) ? k3 : k2;
    const u64 km = (kb > ka) ? kb : ka;  // max val, ties -> smaller index
    const int gidx = NP - 1 - (int)(km & 0xFFFFFFFFu);
    if (t == 0) fps_idx[b * MP + it] = gidx;
    const float2 cc = sxy[gidx];
    const float ccz = sz[gidx];
    maxv = -1.0f; maxi = base;
#pragma unroll
    for (int j = 0; j < PPT; ++j) {
      const float d = dist2(cx[j], cy[j], cz[j], cc.x, cc.y, ccz);
      mind[j] = fminf(mind[j], d);
      if (mind[j] > maxv) { maxv = mind[j]; maxi = base + j; }
    }
    // ping-pong slots + the single barrier above make write(it+1) safe:
    // it+1 writes the other buffer; it+2 writes this one only after the
    // barrier of it+1, which follows every wave's read of iteration it.
  }
}

// ---------------------------------------------------------------------------
// Kernel 2: radius-kNN. One wave per query (4 waves/block). Compacts all
// within-radius candidates into LDS (ballot compaction), then extracts the
// 32 smallest (d2,idx) keys via wave-wide u64 min-reduction.
// Also writes pos_out and batch_out (exact gathers).
// ---------------------------------------------------------------------------
__global__ __launch_bounds__(256) void knn_kernel(const float* __restrict__ pos,
                                                  const int* __restrict__ fps_idx,
                                                  int* __restrict__ nbr,
                                                  float* __restrict__ pos_out,
                                                  float* __restrict__ batch_out) {
  __shared__ u64 list[4][CAP];
  const int t = threadIdx.x;
  const int w = t >> 6;
  const int lane = t & 63;
  const int qg = blockIdx.x * 4 + w;  // 0..8191
  const int b = qg >> 11;
  const float* p = pos + (size_t)b * NP * 3;
  const int pidx = fps_idx[qg];
  const float qx = p[3 * pidx], qy = p[3 * pidx + 1], qz = p[3 * pidx + 2];

  int base = 0;
  for (int rnd = 0; rnd < NP / 64; ++rnd) {
    const int j = rnd * 64 + lane;
    const float d2 = dist2(p[3 * j], p[3 * j + 1], p[3 * j + 2], qx, qy, qz);
    const bool pred = (d2 <= 0.04f);  // 0.04f == f32(R*R) boundary, exact
    const u64 bal = __ballot(pred);
    if (pred) {
      const int slot = base + (int)__popcll(bal & ((1ull << lane) - 1ull));
      if (slot < CAP) list[w][slot] = ((u64)__float_as_uint(d2) << 32) | (u32)j;
    }
    base += (int)__popcll(bal);
  }
  const int L = base < CAP ? base : CAP;
  __syncthreads();

  u64 mk[8];
#pragma unroll
  for (int s = 0; s < 8; ++s) {
    const int sl = lane + s * 64;
    mk[s] = (sl < L) ? list[w][sl] : ~0ull;
  }
  u64 lmin = mk[0];
#pragma unroll
  for (int s = 1; s < 8; ++s) lmin = (mk[s] < lmin) ? mk[s] : lmin;

  int myNbr = -1;
  for (int r = 0; r < KN; ++r) {
    u64 m = lmin;
#pragma unroll
    for (int off = 32; off >= 1; off >>= 1) {
      u64 om = __shfl_xor(m, off, 64);
      m = (om < m) ? om : m;
    }
    if (m == ~0ull) break;  // wave-uniform: fewer than 32 in-radius
    if (lane == r) myNbr = (int)(m & 0xFFFFFFFFu);
    if (lmin == m) {  // exactly one lane (keys unique)
#pragma unroll
      for (int s = 0; s < 8; ++s) if (mk[s] == m) mk[s] = ~0ull;
      lmin = mk[0];
#pragma unroll
      for (int s = 1; s < 8; ++s) lmin = (mk[s] < lmin) ? mk[s] : lmin;
    }
  }
  if (lane < KN) nbr[(size_t)qg * KN + lane] = myNbr;
  if (lane == 0) {
    pos_out[qg * 3 + 0] = qx;
    pos_out[qg * 3 + 1] = qy;
    pos_out[qg * 3 + 2] = qz;
    batch_out[qg] = (float)b;
  }
}

// ---------------------------------------------------------------------------
// Kernel 3: gather + 3-layer MLP + masked max aggregation.
// Block = 256 threads handles 2 queries (64 neighbor rows). Weights staged
// per-layer into a shared 17KB buffer (W3 streamed in two k-halves).
// Aggregation: relu outputs >= 0 and self-neighbor always valid, so
// 0-initialized atomicMax on float bits is exact.
// ---------------------------------------------------------------------------
__global__ __launch_bounds__(256) void mlp_kernel(
    const float* __restrict__ x, const float* __restrict__ pos,
    const int* __restrict__ fps_idx, const int* __restrict__ nbr,
    const float* __restrict__ W1, const float* __restrict__ b1,
    const float* __restrict__ W2, const float* __restrict__ b2,
    const float* __restrict__ W3, const float* __restrict__ b3,
    float* __restrict__ aggG) {
  __shared__ __align__(16) float inB[64][68];  // 67 cols used (x .. rel)
  __shared__ __align__(16) float hB[64][68];
  __shared__ __align__(16) float wB[4352];     // W1(4288) / W2(4096) / W3-half(4096)
  __shared__ u32 agg[2][128];
  __shared__ int vrow[64];
  const int t = threadIdx.x;
  const int q0 = blockIdx.x * 2;

  ((u32*)agg)[t] = 0u;  // 256 entries exactly
  for (int i = t; i < 1072; i += 256) ((float4*)wB)[i] = ((const float4*)W1)[i];
  {
    const int r = t >> 2, qu = t & 3;
    const int qg = q0 + (r >> 5);
    const int nid = nbr[(size_t)qg * KN + (r & 31)];
    const int gid = (nid < 0) ? 0 : nid;
    const int bb = qg >> 11;
    const float4* xr =
        (const float4*)(x + ((size_t)bb * NP + gid) * FD + qu * 16);
#pragma unroll
    for (int u = 0; u < 4; ++u) {
      float4 v = xr[u];
      inB[r][qu * 16 + u * 4 + 0] = v.x;
      inB[r][qu * 16 + u * 4 + 1] = v.y;
      inB[r][qu * 16 + u * 4 + 2] = v.z;
      inB[r][qu * 16 + u * 4 + 3] = v.w;
    }
    if (qu == 0) {
      vrow[r] = nid;
      const float* p = pos + (size_t)bb * NP * 3;
      const int pidx = fps_idx[qg];
      inB[r][64] = p[3 * gid + 0] - p[3 * pidx + 0];
      inB[r][65] = p[3 * gid + 1] - p[3 * pidx + 1];
      inB[r][66] = p[3 * gid + 2] - p[3 * pidx + 2];
    }
  }
  __syncthreads();

  const int c0a = (t & 3) * 16;  // layers 1-2: 64 channels
  const int ra = t >> 2;         // row 0..63
  {  // ---- layer 1: 67 -> 64, relu ----
    float acc[16];
#pragma unroll
    for (int c = 0; c < 16; ++c) acc[c] = b1[c0a + c];
    for (int k = 0; k < 67; ++k)
      fma16(acc, inB[ra][k], (const float4*)&wB[k * 64 + c0a]);
#pragma unroll
    for (int c = 0; c < 16; ++c) hB[ra][c0a + c] = fmaxf(acc[c], 0.0f);
  }
  __syncthreads();
  for (int i = t; i < 1024; i += 256) ((float4*)wB)[i] = ((const float4*)W2)[i];
  __syncthreads();
  {  // ---- layer 2: 64 -> 64, relu (writes back into inB) ----
    float acc[16];
#pragma unroll
    for (int c = 0; c < 16; ++c) acc[c] = b2[c0a + c];
    for (int k = 0; k < 64; ++k)
      fma16(acc, hB[ra][k], (const float4*)&wB[k * 64 + c0a]);
#pragma unroll
    for (int c = 0; c < 16; ++c) inB[ra][c0a + c] = fmaxf(acc[c], 0.0f);
  }
  __syncthreads();

  // ---- layer 3: 64 -> 128 in two k-halves, then masked max aggregation ----
  const int c0b = (t & 7) * 16;
  const int r0 = (t >> 3) * 2;  // even row pair, never straddles a query
  float acc0[16], acc1[16];
#pragma unroll
  for (int c = 0; c < 16; ++c) { acc0[c] = b3[c0b + c]; acc1[c] = b3[c0b + c]; }
  for (int half = 0; half < 2; ++half) {
    for (int i = t; i < 1024; i += 256)
      ((float4*)wB)[i] = ((const float4*)(W3 + half * 32 * 128))[i];
    __syncthreads();
    for (int k = 0; k < 32; ++k) {
      const float a0 = inB[r0][half * 32 + k];
      const float a1 = inB[r0 + 1][half * 32 + k];
      const float4* wp = (const float4*)&wB[k * 128 + c0b];
      fma16(acc0, a0, wp);
      fma16(acc1, a1, wp);
    }
    __syncthreads();
  }
  {
    const int qq = r0 >> 5;
    const int v0 = vrow[r0], v1 = vrow[r0 + 1];
#pragma unroll
    for (int c = 0; c < 16; ++c) {
      float m = 0.0f;  // == max(0, .) folds the relu; exact (>=1 valid row/query)
      if (v0 >= 0) m = fmaxf(m, acc0[c]);
      if (v1 >= 0) m = fmaxf(m, acc1[c]);
      atomicMax(&agg[qq][c0b + c], __float_as_uint(m));
    }
  }
  __syncthreads();
  aggG[(size_t)(q0 + (t >> 7)) * 128 + (t & 127)] =
      __uint_as_float(agg[t >> 7][t & 127]);
}

// ---------------------------------------------------------------------------
// Kernel 4: out = agg @ Wg + bg. 32 rows/block; Wg staged in two k-halves.
// ---------------------------------------------------------------------------
__global__ __launch_bounds__(256) void wg_kernel(const float* __restrict__ aggG,
                                                 const float* __restrict__ Wg,
                                                 const float* __restrict__ bg,
                                                 float* __restrict__ xout) {
  __shared__ __align__(16) float wL[64 * 128];
  __shared__ __align__(16) float aL[32][132];
  const int t = threadIdx.x;
  const size_t row0 = (size_t)blockIdx.x * 32;
  for (int i = t; i < 1024; i += 256) {
    const int r = i >> 5, qd = i & 31;
    float4 v = ((const float4*)(aggG + (row0 + r) * 128))[qd];
    *((float4*)&aL[r][qd * 4]) = v;
  }
  const int r = t >> 3;
  const int c0 = (t & 7) * 16;
  float acc[16];
#pragma unroll
  for (int c = 0; c < 16; ++c) acc[c] = bg[c0 + c];
  for (int half = 0; half < 2; ++half) {
    __syncthreads();  // protects wL overwrite; also orders aL staging (half 0)
    for (int i = t; i < 2048; i += 256)
      ((float4*)wL)[i] = ((const float4*)(Wg + half * 64 * 128))[i];
    __syncthreads();
    for (int k = 0; k < 64; ++k)
      fma16(acc, aL[r][half * 64 + k], (const float4*)&wL[k * 128 + c0]);
  }
#pragma unroll
  for (int u = 0; u < 4; ++u) {
    float4 v = make_float4(acc[u * 4 + 0], acc[u * 4 + 1], acc[u * 4 + 2],
                           acc[u * 4 + 3]);
    ((float4*)(xout + (row0 + r) * 128 + c0))[u] = v;
  }
}

// ---------------------------------------------------------------------------

extern "C" void kernel_launch(void* const* d_in, const int* in_sizes, int n_in,
                              void* d_out, int out_size, void* d_ws,
                              size_t ws_size, hipStream_t stream) {
  const float* x   = (const float*)d_in[0];
  const float* pos = (const float*)d_in[1];
  // d_in[2] = batch (implied by layout, unused)
  const float* W1 = (const float*)d_in[3];
  const float* b1 = (const float*)d_in[4];
  const float* W2 = (const float*)d_in[5];
  const float* b2 = (const float*)d_in[6];
  const float* W3 = (const float*)d_in[7];
  const float* b3 = (const float*)d_in[8];
  const float* Wg = (const float*)d_in[9];
  const float* bg = (const float*)d_in[10];

  float* out = (float*)d_out;
  float* x_out = out;                                  // 8192*128
  float* pos_out = out + (size_t)NB * MP * 128;        // 8192*3
  float* batch_out = pos_out + (size_t)NB * MP * 3;    // 8192 (as float)

  char* ws = (char*)d_ws;
  int* fps_idx = (int*)ws;                             // 8192 ints
  int* nbr = (int*)(ws + 32768);                       // 8192*32 ints = 1 MB
  float* aggG = (float*)(ws + 32768 + (size_t)NB * MP * KN * 4);  // 4 MB

  hipLaunchKernelGGL(fps_kernel, dim3(NB), dim3(256), 0, stream, pos, fps_idx);
  hipLaunchKernelGGL(knn_kernel, dim3(NB * MP / 4), dim3(256), 0, stream, pos,
                     fps_idx, nbr, pos_out, batch_out);
  hipLaunchKernelGGL(mlp_kernel, dim3(NB * MP / 2), dim3(256), 0, stream, x,
                     pos, fps_idx, nbr, W1, b1, W2, b2, W3, b3, aggG);
  hipLaunchKernelGGL(wg_kernel, dim3(NB * MP / 32), dim3(256), 0, stream, aggG,
                     Wg, bg, x_out);
}